// Round 1
// baseline (235.933 us; speedup 1.0000x reference)
//
#include <hip/hip_runtime.h>

typedef _Float16 f16;
typedef _Float16 f16x8 __attribute__((ext_vector_type(8)));
typedef float f32x4 __attribute__((ext_vector_type(4)));

#define INV_R (1.0f / 40.0f)

// ---- workspace layout (bytes), total ~11.4 MB ----
#define OFF_HT   0u              // f16 [80][512]   h transposed (cols=n) for stage-1 B
#define OFF_B0   81920u          // f32 [64]        layer-0 bias (zeros ++ bf)
#define OFF_K0   82176u          // f16 [64][4320]  layer-0 fused kernel (conv|dense)
#define OFF_K1   635136u         // f16 [64][4160]
#define OFF_K2   1167616u
#define OFF_K3   1700096u
#define OFF_K4   2232576u        // f16 [16][4160]
#define OFF_TA   2365696u        // f16 [512][4320] t ping
#define OFF_TB   6789376u        // f16 [512][4160] t pong
#define OFF_OA   11049216u       // f32 [512][64]   out ping
#define OFF_OB   11180288u       // f32 [512][64]   out pong

__device__ __forceinline__ float feats0_val(int ch, int n, const float* v, const float* other) {
  if (ch == 0) return 1.0f;
  if (ch < 4) return v[n * 3 + (ch - 1)];
  return other[n * 62 + (ch - 4)];
}

// one-shot conversion / packing kernel
__global__ void prep_kernel(const float* __restrict__ v, const float* __restrict__ other,
                            const float* __restrict__ kf, const float* __restrict__ Wf,
                            const float* __restrict__ bf,
                            const float* __restrict__ k1, const float* __restrict__ W1,
                            const float* __restrict__ k2, const float* __restrict__ W2,
                            const float* __restrict__ k3, const float* __restrict__ W3,
                            const float* __restrict__ k4, const float* __restrict__ W4,
                            char* __restrict__ ws) {
  int idx = blockIdx.x * 256 + threadIdx.x;
  if (idx < 40960) {                       // hT: feats0 transposed, rows 66..79 zero
    int i = idx >> 9, n = idx & 511;
    float val = (i < 66) ? feats0_val(i, n, v, other) : 0.0f;
    ((f16*)(ws + OFF_HT))[idx] = (f16)val;
    return;
  }
  idx -= 40960;
  if (idx < 49152) {                       // tA dense-tail: feats0 per m, pad to 96
    int m = idx / 96, j = idx % 96;
    float val = (j < 66) ? feats0_val(j, m, v, other) : 0.0f;
    ((f16*)(ws + OFF_TA))[m * 4320 + 4224 + j] = (f16)val;
    return;
  }
  idx -= 49152;
  if (idx < 276480) {                      // K0: rows 0..31 conv (k'=i*64+g == flat), rows 32..63 dense tail
    int o = idx / 4320, k = idx % 4320;
    float val = 0.0f;
    if (o < 32) { if (k < 4224) val = kf[o * 4224 + k]; }
    else if (k >= 4224 && k < 4290) val = Wf[(o - 32) * 66 + (k - 4224)];
    ((f16*)(ws + OFF_K0))[idx] = (f16)val;
    return;
  }
  idx -= 276480;
  if (idx < 798720) {                      // K1..K3: conv flat ++ dense W tail
    int which = idx / 266240, e = idx % 266240;
    const float* kk = which == 0 ? k1 : (which == 1 ? k2 : k3);
    const float* WW = which == 0 ? W1 : (which == 1 ? W2 : W3);
    int o = e / 4160, k = e % 4160;
    float val = (k < 4096) ? kk[o * 4096 + k] : WW[o * 64 + (k - 4096)];
    ((f16*)(ws + OFF_K1 + (unsigned)which * 532480u))[e] = (f16)val;
    return;
  }
  idx -= 798720;
  if (idx < 66560) {                       // K4 (6 rows + zero pad rows to 16)
    int o = idx / 4160, k = idx % 4160;
    float val = 0.0f;
    if (o < 6) val = (k < 4096) ? k4[o * 4096 + k] : W4[o * 64 + (k - 4096)];
    ((f16*)(ws + OFF_K4))[idx] = (f16)val;
    return;
  }
  idx -= 66560;
  if (idx < 64) ((float*)(ws + OFF_B0))[idx] = (idx < 32) ? 0.0f : bf[idx - 32];
}

// minimax atan on [-1,1], abs err ~2e-6
__device__ __forceinline__ float atan_poly(float t) {
  float t2 = t * t;
  float p = -0.0117212f;
  p = p * t2 + 0.05265332f;
  p = p * t2 - 0.11643287f;
  p = p * t2 + 0.19354346f;
  p = p * t2 - 0.33262347f;
  p = p * t2 + 0.99997726f;
  return t * p;
}

// grid_sample axis weights, size=4, align_corners=False, zero padding
__device__ __forceinline__ void axis_w(float g, int& i0c, int& i1c, float& w0, float& w1) {
  float c = 2.0f * g + 1.5f;
  float fl = floorf(c);
  float f = c - fl;
  int i0 = (int)fl;
  w0 = (i0 >= 0 && i0 <= 3) ? (1.0f - f) : 0.0f;   // tap at i0 (zero if out of range)
  w1 = (i0 >= -1 && i0 <= 2) ? f : 0.0f;           // tap at i0+1
  i0c = min(max(i0, 0), 3);
  i1c = min(max(i0 + 1, 0), 3);
}

// stage 1: per output point m, build W[g][n] in LDS (scatter, collision-free by n),
// then t[g,i] = W @ hT^T via MFMA. Stores t as [m][i*64+g] fp16.
template<int CI, int ITILES, int KDIM>
__global__ __launch_bounds__(256) void stage1_kernel(const float* __restrict__ p,
                                                     const float* __restrict__ mask,
                                                     const f16* __restrict__ hT,
                                                     f16* __restrict__ tout) {
  __shared__ f16 Wlds[64 * 512];   // 64 KB, rows XOR-swizzled in n by ((g&7)<<3)
  int tid = threadIdx.x;
  int m = blockIdx.x;
  int4* wz4 = (int4*)Wlds;
  int4 zero4 = make_int4(0, 0, 0, 0);
  #pragma unroll
  for (int i = 0; i < 16; ++i) wz4[tid + i * 256] = zero4;
  float pmx = p[m * 3 + 0], pmy = p[m * 3 + 1], pmz = p[m * 3 + 2];
  __syncthreads();
  #pragma unroll
  for (int rep = 0; rep < 2; ++rep) {
    int n = rep * 256 + tid;
    float x = (p[n * 3 + 0] - pmx) * INV_R;
    float y = (p[n * 3 + 1] - pmy) * INV_R;
    float z = (p[n * 3 + 2] - pmz) * INV_R;
    float r2 = x * x + y * y + z * z;
    float q = 1.0f - r2;
    float att = (q > 0.0f) ? q * q * q * mask[n] : 0.0f;
    // map_polar_sqr
    float ax = fabsf(x), ay = fabsf(y);
    bool c1 = (x == 0.0f) && (y == 0.0f);
    bool c2 = (ay <= ax) && !c1;
    float r = sqrtf(x * x + y * y + 1e-9f);
    float num = c2 ? y : x;
    float den = c2 ? x : y;
    float a = atan_poly(num / den);        // NaN only when c1 (selected away)
    float s2 = copysignf(r, x), s3 = copysignf(r, y);
    const float C4PI = 1.2732395447351628f;
    float xs = c1 ? 0.0f : (c2 ? s2 : C4PI * s3 * a);
    float ys = c1 ? 0.0f : (c2 ? C4PI * s2 * a : s3);
    float zs = z;
    int iz0, iz1, iy0, iy1, ix0, ix1;
    float wz0, wz1, wy0, wy1, wx0, wx1;
    axis_w(zs, iz0, iz1, wz0, wz1);        // z -> kD (g high)
    axis_w(ys, iy0, iy1, wy0, wy1);        // y -> kH
    axis_w(xs, ix0, ix1, wx0, wx1);        // x -> kW (g low)
    wz0 *= att; wz1 *= att;
    int gz[2] = {iz0 * 16, iz1 * 16};
    int gy[2] = {iy0 * 4, iy1 * 4};
    int gx[2] = {ix0, ix1};
    float wzv[2] = {wz0, wz1}, wyv[2] = {wy0, wy1}, wxv[2] = {wx0, wx1};
    #pragma unroll
    for (int za = 0; za < 2; ++za)
      #pragma unroll
      for (int ya = 0; ya < 2; ++ya)
        #pragma unroll
        for (int xa = 0; xa < 2; ++xa) {
          float w = wzv[za] * wyv[ya] * wxv[xa];
          if (w != 0.0f) {   // skip zeros: LDS pre-zeroed, avoids clamped-index overwrite
            int g = gz[za] + gy[ya] + gx[xa];
            Wlds[g * 512 + (n ^ ((g & 7) << 3))] = (f16)w;
          }
        }
  }
  __syncthreads();
  // MFMA: wave w owns g-rows [16w,16w+16); tiles over i; K = n = 512
  int wave = tid >> 6, lane = tid & 63;
  int row = lane & 15, kgrp = lane >> 4;
  int grow = wave * 16 + row;
  f32x4 acc[ITILES];
  #pragma unroll
  for (int it = 0; it < ITILES; ++it) acc[it] = f32x4{0.f, 0.f, 0.f, 0.f};
  for (int k0 = 0; k0 < 512; k0 += 32) {
    int n0 = k0 + kgrp * 8;
    f16x8 afrag = *(f16x8*)&Wlds[grow * 512 + (n0 ^ ((grow & 7) << 3))];
    #pragma unroll
    for (int it = 0; it < ITILES; ++it) {
      int icol = it * 16 + row;
      f16x8 bfrag = *(const f16x8*)&hT[icol * 512 + n0];
      acc[it] = __builtin_amdgcn_mfma_f32_16x16x32_f16(afrag, bfrag, acc[it], 0, 0, 0);
    }
  }
  int g4 = wave * 16 + kgrp * 4;
  #pragma unroll
  for (int it = 0; it < ITILES; ++it) {
    int icol = it * 16 + row;
    if (icol < CI) {
      union { f16 h[4]; ushort4 u; } cv;
      #pragma unroll
      for (int r = 0; r < 4; ++r) cv.h[r] = (f16)acc[it][r];
      *(ushort4*)&tout[(size_t)m * KDIM + icol * 64 + g4] = cv.u;   // [m][i*64+g]
    }
  }
}

// stage 2: out[m,o] = t[m,:] . Kf[o,:] (conv + fused dense tail), 4-way K-split + LDS reduce,
// epilogue: +bias (+residual), write out32, and emit next layer's fp16 operands.
template<int KDIM, int NT, bool RES, bool FINAL>
__global__ __launch_bounds__(NT * 256) void stage2_kernel(
    const f16* __restrict__ t, const f16* __restrict__ Kf,
    const float* __restrict__ bias, const float* __restrict__ res,
    float* __restrict__ out32, f16* __restrict__ hT, f16* __restrict__ tnext,
    float* __restrict__ dout) {
  constexpr int KSTEPS = KDIM / 32;
  constexpr int KW = 4;
  __shared__ float red[KW - 1][NT][256];
  int tid = threadIdx.x;
  int wave = tid >> 6, lane = tid & 63;
  int otile = wave % NT, kpart = wave / NT;
  int row = lane & 15, kgrp = lane >> 4;
  int mrow = blockIdx.x * 16 + row;
  int ocol = otile * 16 + row;
  f32x4 acc = {0.f, 0.f, 0.f, 0.f};
  for (int ks = kpart; ks < KSTEPS; ks += KW) {
    int k0 = ks * 32 + kgrp * 8;
    f16x8 afrag = *(const f16x8*)&t[(size_t)mrow * KDIM + k0];
    f16x8 bfrag = *(const f16x8*)&Kf[(size_t)ocol * KDIM + k0];
    acc = __builtin_amdgcn_mfma_f32_16x16x32_f16(afrag, bfrag, acc, 0, 0, 0);
  }
  if (kpart > 0) {
    #pragma unroll
    for (int r = 0; r < 4; ++r)
      red[kpart - 1][otile][(kgrp * 4 + r) * 16 + row] = acc[r];
  }
  __syncthreads();
  if (kpart == 0) {
    #pragma unroll
    for (int kw = 0; kw < KW - 1; ++kw)
      #pragma unroll
      for (int r = 0; r < 4; ++r)
        acc[r] += red[kw][otile][(kgrp * 4 + r) * 16 + row];
    #pragma unroll
    for (int r = 0; r < 4; ++r) {
      int mm = blockIdx.x * 16 + kgrp * 4 + r;
      int oo = otile * 16 + row;
      if (FINAL) {
        if (oo < 6) dout[mm * 6 + oo] = acc[r] + bias[oo];
      } else {
        float val = acc[r] + bias[oo];
        if (RES) val += res[mm * 64 + oo];
        out32[mm * 64 + oo] = val;
        float h = fmaxf(val, 0.0f);
        hT[oo * 512 + mm] = (f16)h;                       // next stage-1 B operand
        tnext[(size_t)mm * 4160 + 4096 + oo] = (f16)h;    // next stage-2 dense tail
      }
    }
  }
}

extern "C" void kernel_launch(void* const* d_in, const int* in_sizes, int n_in,
                              void* d_out, int out_size, void* d_ws, size_t ws_size,
                              hipStream_t stream) {
  const float* p     = (const float*)d_in[0];
  const float* v     = (const float*)d_in[1];
  const float* other = (const float*)d_in[2];
  const float* mask  = (const float*)d_in[3];
  const float* kf    = (const float*)d_in[4];
  const float* Wf    = (const float*)d_in[5];
  const float* bf    = (const float*)d_in[6];
  const float* k1    = (const float*)d_in[7];
  const float* W1    = (const float*)d_in[8];
  const float* b1    = (const float*)d_in[9];
  const float* k2    = (const float*)d_in[10];
  const float* W2    = (const float*)d_in[11];
  const float* b2    = (const float*)d_in[12];
  const float* k3    = (const float*)d_in[13];
  const float* W3    = (const float*)d_in[14];
  const float* b3    = (const float*)d_in[15];
  const float* k4    = (const float*)d_in[16];
  const float* W4    = (const float*)d_in[17];
  const float* b4    = (const float*)d_in[18];
  (void)in_sizes; (void)n_in; (void)out_size; (void)ws_size;

  char* ws = (char*)d_ws;
  f16* hT       = (f16*)(ws + OFF_HT);
  float* bias0  = (float*)(ws + OFF_B0);
  const f16* K0p = (const f16*)(ws + OFF_K0);
  const f16* K1p = (const f16*)(ws + OFF_K1);
  const f16* K2p = (const f16*)(ws + OFF_K2);
  const f16* K3p = (const f16*)(ws + OFF_K3);
  const f16* K4p = (const f16*)(ws + OFF_K4);
  f16* tA   = (f16*)(ws + OFF_TA);
  f16* tB   = (f16*)(ws + OFF_TB);
  float* outA = (float*)(ws + OFF_OA);
  float* outB = (float*)(ws + OFF_OB);

  prep_kernel<<<4813, 256, 0, stream>>>(v, other, kf, Wf, bf, k1, W1, k2, W2, k3, W3, k4, W4, ws);

  // layer 0 (Ci=66 -> concat(oc32, od32))
  stage1_kernel<66, 5, 4320><<<512, 256, 0, stream>>>(p, mask, hT, tA);
  stage2_kernel<4320, 4, false, false><<<32, 1024, 0, stream>>>(tA, K0p, bias0, nullptr, outA, hT, tB, nullptr);
  // layer 1
  stage1_kernel<64, 4, 4160><<<512, 256, 0, stream>>>(p, mask, hT, tB);
  stage2_kernel<4160, 4, true, false><<<32, 1024, 0, stream>>>(tB, K1p, b1, outA, outB, hT, tA, nullptr);
  // layer 2
  stage1_kernel<64, 4, 4160><<<512, 256, 0, stream>>>(p, mask, hT, tA);
  stage2_kernel<4160, 4, true, false><<<32, 1024, 0, stream>>>(tA, K2p, b2, outB, outA, hT, tB, nullptr);
  // layer 3
  stage1_kernel<64, 4, 4160><<<512, 256, 0, stream>>>(p, mask, hT, tB);
  stage2_kernel<4160, 4, true, false><<<32, 1024, 0, stream>>>(tB, K3p, b3, outA, outB, hT, tA, nullptr);
  // layer 4 (Co=6, no residual) -> d_out
  stage1_kernel<64, 4, 4160><<<512, 256, 0, stream>>>(p, mask, hT, tA);
  stage2_kernel<4160, 1, false, true><<<32, 256, 0, stream>>>(tA, K4p, b4, nullptr, nullptr, nullptr, nullptr, (float*)d_out);
}